// Round 14
// baseline (692.568 us; speedup 1.0000x reference)
//
#include <hip/hip_runtime.h>
#include <math.h>

#define NNODES 50000
#define NEG_SLOPE 0.2f

typedef unsigned short ushort8v __attribute__((ext_vector_type(8)));
typedef unsigned short ushort4v __attribute__((ext_vector_type(4)));
typedef short short8v __attribute__((ext_vector_type(8)));
typedef float f32x4 __attribute__((ext_vector_type(4)));
typedef float f32x2 __attribute__((ext_vector_type(2)));

__device__ __forceinline__ unsigned short f2bf(float f){
    unsigned u = __float_as_uint(f);
    u += 0x7fff + ((u >> 16) & 1);   // RNE; inputs finite
    return (unsigned short)(u >> 16);
}

// ---------------- prep helpers ----------------
__device__ __forceinline__ void emit_wa(const float* __restrict__ W, const float* __restrict__ a_s,
                                        const float* __restrict__ a_d, unsigned short* __restrict__ Wt,
                                        int Kin, int C, int id){
    const int n = id / Kin, k = id - n * Kin;
    float v = 0.f;
    if(n < 8){
        const int hh = n & 3;
        const float* av = (n < 4) ? a_s : a_d;
        for(int c = 0; c < C; c++) v += W[(size_t)k * (4 * C) + hh * C + c] * av[hh * C + c];
    }
    Wt[id] = f2bf(v);
}

__device__ __forceinline__ void emit_wc(const float* __restrict__ W, unsigned short* __restrict__ Wt,
                                        int Kin, int C, int id){
    const int c = id / (4 * Kin);
    const int hk = id - c * (4 * Kin);
    const int h = hk / Kin, k = hk - h * Kin;
    const float v = (c < C) ? W[(size_t)k * (4 * C) + h * C + c] * 0.25f : 0.f;
    Wt[id] = f2bf(v);
}

// ---------------- init+prep: detect + zero deg/bins + xbf + Wa* + Wc* ----------------
__global__ void initprep_kernel(const unsigned long long* __restrict__ e, int* __restrict__ flag,
                                int* __restrict__ deg, int* __restrict__ bincnt, int N,
                                const float* __restrict__ x, unsigned short* __restrict__ xbf, int X4,
                                const float* __restrict__ W1, const float* __restrict__ as1, const float* __restrict__ ad1,
                                const float* __restrict__ W2, const float* __restrict__ as2, const float* __restrict__ ad2,
                                const float* __restrict__ W3, const float* __restrict__ as3, const float* __restrict__ ad3,
                                unsigned short* __restrict__ Wa1, unsigned short* __restrict__ Wa2,
                                unsigned short* __restrict__ Wa3, unsigned short* __restrict__ Wc1,
                                unsigned short* __restrict__ Wc2, unsigned short* __restrict__ Wc3){
    if(blockIdx.x == 0 && threadIdx.x < 64){
        const unsigned long long v = e[threadIdx.x];
        const unsigned long long mask = __ballot(v >= (1ULL << 32));
        if(threadIdx.x == 0) *flag = (mask == 0ULL) ? 1 : 0;
    }
    int id = blockIdx.x * blockDim.x + threadIdx.x;
    if(id < 256) bincnt[id] = 0;
    if(id < N) deg[id] = 0;
    if(id < X4){
        const float4 v = *(const float4*)&x[(size_t)id * 4];
        ushort4v o;
        o[0] = f2bf(v.x); o[1] = f2bf(v.y); o[2] = f2bf(v.z); o[3] = f2bf(v.w);
        *(ushort4v*)&xbf[(size_t)id * 4] = o;
        return;
    }
    id -= X4;
    if(id < 16 * 128){ emit_wa(W1, as1, ad1, Wa1, 128, 64, id); return; }
    id -= 16 * 128;
    if(id < 16 * 64){ emit_wa(W2, as2, ad2, Wa2, 64, 64, id); return; }
    id -= 16 * 64;
    if(id < 16 * 64){ emit_wa(W3, as3, ad3, Wa3, 64, 40, id); return; }
    id -= 16 * 64;
    if(id < 64 * 512){ emit_wc(W1, Wc1, 128, 64, id); return; }
    id -= 64 * 512;
    if(id < 64 * 256){ emit_wc(W2, Wc2, 64, 64, id); return; }
    id -= 64 * 256;
    if(id < 48 * 256){ emit_wc(W3, Wc3, 64, 40, id); }
}

// ---------------- histogram off the raw edge buffer ----------------
__global__ void hist_kernel(const void* __restrict__ e, const int* __restrict__ flag,
                            int* __restrict__ deg, int E){
    const int i = blockIdx.x * blockDim.x + threadIdx.x;
    if(i < E){
        const int d = (*flag) ? (int)((const long long*)e)[E + i] : ((const int*)e)[E + i];
        atomicAdd(&deg[d], 1);
    }
}

// ---------------- CSR build (hierarchical scan) + degree-bin histogram ----------------
__global__ __launch_bounds__(512) void scan1_kernel(const int* __restrict__ deg,
                                                    int* __restrict__ excl,
                                                    int* __restrict__ bsum,
                                                    int* __restrict__ bincnt, int n){
    __shared__ int sh[512];
    const int t = threadIdx.x;
    const int gid = blockIdx.x * 512 + t;
    const int v = (gid < n) ? deg[gid] : 0;
    if(gid < n) atomicAdd(&bincnt[min(v, 255)], 1);
    sh[t] = v;
    __syncthreads();
    for(int off = 1; off < 512; off <<= 1){
        const int add = (t >= off) ? sh[t - off] : 0;
        __syncthreads();
        sh[t] += add;
        __syncthreads();
    }
    if(gid < n) excl[gid] = sh[t] - v;
    if(t == 511) bsum[blockIdx.x] = sh[511];
}

// scan block sums (ascending, exclusive) AND degree bins (descending suffix-exclusive)
__global__ __launch_bounds__(256) void scan2_kernel(int* __restrict__ bsum, int nb,
                                                    int* __restrict__ bincnt,
                                                    int* __restrict__ bincur){
    __shared__ int sh[256];
    __shared__ int sb[256];
    const int t = threadIdx.x;
    const int v = (t < nb) ? bsum[t] : 0;
    sh[t] = v;
    const int c = bincnt[t];
    sb[t] = c;
    __syncthreads();
    for(int off = 1; off < 256; off <<= 1){
        const int addA = (t >= off) ? sh[t - off] : 0;
        const int addB = (t + off < 256) ? sb[t + off] : 0;
        __syncthreads();
        sh[t] += addA;
        sb[t] += addB;
        __syncthreads();
    }
    if(t < nb) bsum[t] = sh[t] - v;    // exclusive prefix
    bincur[t] = sb[t] - c;             // exclusive suffix: nodes with larger degree first
}

__global__ void scan3_kernel(const int* __restrict__ excl, const int* __restrict__ bsum,
                             const int* __restrict__ deg,
                             int* __restrict__ row_ptr, int* __restrict__ cursor,
                             int* __restrict__ bincur, int* __restrict__ perm,
                             int n, int E){
    const int gid = blockIdx.x * blockDim.x + threadIdx.x;
    if(gid < n){
        const int r = excl[gid] + bsum[gid >> 9];
        row_ptr[gid] = r;
        cursor[gid] = r;
        const int pos = atomicAdd(&bincur[min(deg[gid], 255)], 1);
        perm[pos] = gid;
    }
    if(gid == 0) row_ptr[n] = E;
}

__global__ void scatter_kernel(const void* __restrict__ e, const int* __restrict__ flag,
                               int* __restrict__ cursor, int* __restrict__ col, int E){
    const int i = blockIdx.x * blockDim.x + threadIdx.x;
    if(i < E){
        int s, d;
        if(*flag){ s = (int)((const long long*)e)[i]; d = (int)((const long long*)e)[E + i]; }
        else     { s = ((const int*)e)[i];            d = ((const int*)e)[E + i]; }
        const int pos = atomicAdd(&cursor[d], 1);
        col[pos] = s;
    }
}

// ---------------- alpha GEMM (layer 1 only): ea/ed = exp(A @ Wa) ----------------
template<int K>
__global__ __launch_bounds__(256) void agemm_kernel(const unsigned short* __restrict__ A,
                                                    const unsigned short* __restrict__ Wa,
                                                    float* __restrict__ ea, float* __restrict__ ed,
                                                    int M){
    const int lane = threadIdx.x & 63;
    const int wave = threadIdx.x >> 6;
    const int quad = lane >> 4;
    const int l16 = lane & 15;
    const int bm = blockIdx.x * 64;
    const int m = min(bm + wave * 16 + l16, M - 1);
    f32x4 acc = {0,0,0,0};
    #pragma unroll
    for(int k0 = 0; k0 < K; k0 += 32){
        const short8v a = *(const short8v*)&A[(size_t)m * K + k0 + quad * 8];
        const short8v b = *(const short8v*)&Wa[(size_t)l16 * K + k0 + quad * 8];
        acc = __builtin_amdgcn_mfma_f32_16x16x32_bf16(a, b, acc, 0, 0, 0);
    }
    if(l16 < 8){
        const int h = l16 & 3;
        float* dst = (l16 < 4) ? ea : ed;
        const int rbase = bm + wave * 16 + quad * 4;
        #pragma unroll
        for(int r = 0; r < 4; r++){
            const int row = rbase + r;
            if(row < M){
                const float v = acc[r];
                *(f32x2*)&dst[(size_t)row * 8 + 2 * h] = (f32x2){__expf(v), __expf(NEG_SLOPE * v)};
            }
        }
    }
}

// ---------------- gather RAW features (r9 shape) over degree-sorted perm ----------------
template<int K>
__global__ __launch_bounds__(256) void gather_kernel(const unsigned short* __restrict__ X,
                                                     const int* __restrict__ row_ptr,
                                                     const int* __restrict__ col,
                                                     const int* __restrict__ perm,
                                                     const float* __restrict__ ea,
                                                     const float* __restrict__ ed,
                                                     unsigned short* __restrict__ g){
    constexpr int CPL = K / 16;       // channels per lane: 8 or 4
    constexpr int PAIRS = CPL / 2;
    const int lane = threadIdx.x & 63;
    const int wave = threadIdx.x >> 6;
    const int n = perm[blockIdx.x * 4 + wave];   // 4 equal-degree nodes per block
    const int slot = lane >> 4;
    const int pos = lane & 15;
    const int rs = row_ptr[n], re = row_ptr[n + 1];
    const int T = re - rs + 1;        // edges + virtual self loop
    const float4 edA = *(const float4*)&ed[(size_t)n * 8];
    const float4 edB = *(const float4*)&ed[(size_t)n * 8 + 4];

    f32x2 acc[4][PAIRS];
    #pragma unroll
    for(int h = 0; h < 4; h++)
        #pragma unroll
        for(int p = 0; p < PAIRS; p++) acc[h][p] = (f32x2){0.f, 0.f};
    float dnm[4] = {0.f, 0.f, 0.f, 0.f};

    auto body = [&](int e){
        const int s = (e < re) ? col[e] : n;   // e==re => self loop
        const float4 eaA = *(const float4*)&ea[(size_t)s * 8];
        const float4 eaB = *(const float4*)&ea[(size_t)s * 8 + 4];
        const float w0 = fmaxf(eaA.x * edA.x, eaA.y * edA.y);
        const float w1 = fmaxf(eaA.z * edA.z, eaA.w * edA.w);
        const float w2 = fmaxf(eaB.x * edB.x, eaB.y * edB.y);
        const float w3 = fmaxf(eaB.z * edB.z, eaB.w * edB.w);
        dnm[0] += w0; dnm[1] += w1; dnm[2] += w2; dnm[3] += w3;
        unsigned u[PAIRS];
        if constexpr(PAIRS == 2){
            const uint2 t2 = *(const uint2*)&X[(size_t)s * K + pos * CPL];
            u[0] = t2.x; u[1] = t2.y;
        } else {
            const uint4 t4 = *(const uint4*)&X[(size_t)s * K + pos * CPL];
            u[0] = t4.x; u[1] = t4.y; u[2] = t4.z; u[3] = t4.w;
        }
        #pragma unroll
        for(int p = 0; p < PAIRS; p++){
            const f32x2 v = {__uint_as_float(u[p] << 16), __uint_as_float(u[p] & 0xffff0000u)};
            acc[0][p] += (f32x2){w0, w0} * v;
            acc[1][p] += (f32x2){w1, w1} * v;
            acc[2][p] += (f32x2){w2, w2} * v;
            acc[3][p] += (f32x2){w3, w3} * v;
        }
    };

    int k = 0;
    for(; k + 8 <= T; k += 8){ body(rs + k + slot); body(rs + k + 4 + slot); }
    for(; k + 4 <= T; k += 4){ body(rs + k + slot); }
    if(k < T && slot < T - k){ body(rs + k + slot); }

    #pragma unroll
    for(int msk = 16; msk < 64; msk <<= 1){
        #pragma unroll
        for(int h = 0; h < 4; h++){
            #pragma unroll
            for(int p = 0; p < PAIRS; p++){
                acc[h][p][0] += __shfl_xor(acc[h][p][0], msk);
                acc[h][p][1] += __shfl_xor(acc[h][p][1], msk);
            }
            dnm[h] += __shfl_xor(dnm[h], msk);
        }
    }
    if(lane < 16){
        #pragma unroll
        for(int h = 0; h < 4; h++){
            const float sc = 1.f / dnm[h];
            if constexpr(PAIRS == 2){
                ushort4v o;
                o[0] = f2bf(acc[h][0][0] * sc); o[1] = f2bf(acc[h][0][1] * sc);
                o[2] = f2bf(acc[h][1][0] * sc); o[3] = f2bf(acc[h][1][1] * sc);
                *(ushort4v*)&g[(size_t)n * (4 * K) + h * K + pos * CPL] = o;
            } else {
                ushort8v o;
                #pragma unroll
                for(int p = 0; p < 4; p++){
                    o[2*p]   = f2bf(acc[h][p][0] * sc);
                    o[2*p+1] = f2bf(acc[h][p][1] * sc);
                }
                *(ushort8v*)&g[(size_t)n * (4 * K) + h * K + pos * CPL] = o;
            }
        }
    }
}

// ---------------- post-aggregation GEMM (+fused next-layer alpha) ----------------
template<int KC, int NC, bool FINAL, bool ALPHA>
__global__ __launch_bounds__(256) void pgemm_kernel(const unsigned short* __restrict__ A,
                                                    const unsigned short* __restrict__ Bt,
                                                    const float* __restrict__ bias,
                                                    void* __restrict__ outv,
                                                    const unsigned short* __restrict__ Wa,
                                                    float* __restrict__ ea,
                                                    float* __restrict__ ed,
                                                    int M){
    constexpr int NT = (NC + 15) / 16;   // 4 (NC=64) or 3 (NC=40)
    __shared__ unsigned short lh[ALPHA ? 4 : 1][16][72];
    const int lane = threadIdx.x & 63;
    const int wave = threadIdx.x >> 6;
    const int quad = lane >> 4;
    const int l16 = lane & 15;
    const int bm = blockIdx.x * 64;
    const int m = min(bm + wave * 16 + l16, M - 1);
    const size_t arow = (size_t)m * KC;

    f32x4 acc[NT];
    #pragma unroll
    for(int t = 0; t < NT; t++) acc[t] = (f32x4){0,0,0,0};

    for(int k0 = 0; k0 < KC; k0 += 32){
        const short8v a = *(const short8v*)&A[arow + k0 + quad * 8];
        #pragma unroll
        for(int t = 0; t < NT; t++){
            const short8v b = *(const short8v*)&Bt[(size_t)(t * 16 + l16) * KC + k0 + quad * 8];
            acc[t] = __builtin_amdgcn_mfma_f32_16x16x32_bf16(a, b, acc[t], 0, 0, 0);
        }
    }
    const int rbase = bm + wave * 16 + quad * 4;
    if(!FINAL){
        unsigned short* out = (unsigned short*)outv;
        #pragma unroll
        for(int t = 0; t < NT; t++){
            const int c = t * 16 + l16;
            #pragma unroll
            for(int r = 0; r < 4; r++){
                const unsigned short hb = f2bf(fmaxf(acc[t][r] + bias[c], 0.f));
                const int row = rbase + r;
                if(row < M) out[(size_t)row * NC + c] = hb;
                if constexpr(ALPHA) lh[wave][quad * 4 + r][c] = hb;
            }
        }
        if constexpr(ALPHA){
            f32x4 a4 = {0, 0, 0, 0};
            #pragma unroll
            for(int k0 = 0; k0 < 64; k0 += 32){
                const short8v a = *(const short8v*)&lh[wave][l16][k0 + quad * 8];
                const short8v b = *(const short8v*)&Wa[(size_t)l16 * 64 + k0 + quad * 8];
                a4 = __builtin_amdgcn_mfma_f32_16x16x32_bf16(a, b, a4, 0, 0, 0);
            }
            if(l16 < 8){
                const int h = l16 & 3;
                float* dst = (l16 < 4) ? ea : ed;
                #pragma unroll
                for(int r = 0; r < 4; r++){
                    const int row = rbase + r;
                    if(row < M){
                        const float v = a4[r];
                        *(f32x2*)&dst[(size_t)row * 8 + 2 * h] = (f32x2){__expf(v), __expf(NEG_SLOPE * v)};
                    }
                }
            }
        }
    } else {
        float* out = (float*)outv;
        float o[NT][4];
        #pragma unroll
        for(int t = 0; t < NT; t++){
            const int c = t * 16 + l16;
            const bool valid = c < 40;
            const float bc = valid ? bias[c] : 0.f;
            #pragma unroll
            for(int r = 0; r < 4; r++)
                o[t][r] = valid ? fmaxf(acc[t][r] + bc, 0.f) : -INFINITY;
        }
        #pragma unroll
        for(int r = 0; r < 4; r++){
            float mx = o[0][r];
            #pragma unroll
            for(int t = 1; t < NT; t++) mx = fmaxf(mx, o[t][r]);
            #pragma unroll
            for(int off = 1; off < 16; off <<= 1) mx = fmaxf(mx, __shfl_xor(mx, off));
            float se = 0.f;
            #pragma unroll
            for(int t = 0; t < NT; t++) se += (o[t][r] > -INFINITY) ? __expf(o[t][r] - mx) : 0.f;
            #pragma unroll
            for(int off = 1; off < 16; off <<= 1) se += __shfl_xor(se, off);
            const float lz = mx + logf(se);
            const int row = rbase + r;
            if(row < M){
                #pragma unroll
                for(int t = 0; t < NT; t++){
                    const int c = t * 16 + l16;
                    if(c < 40) out[(size_t)row * 40 + c] = o[t][r] - lz;
                }
            }
        }
    }
}

// ---------------- driver ----------------
extern "C" void kernel_launch(void* const* d_in, const int* in_sizes, int n_in,
                              void* d_out, int out_size, void* d_ws, size_t ws_size,
                              hipStream_t stream){
    const int N = NNODES;
    const int E = in_sizes[1] / 2;

    const float* x   = (const float*)d_in[0];
    const float* W1  = (const float*)d_in[2];
    const float* as1 = (const float*)d_in[3];
    const float* ad1 = (const float*)d_in[4];
    const float* b1  = (const float*)d_in[5];
    const float* W2  = (const float*)d_in[6];
    const float* as2 = (const float*)d_in[7];
    const float* ad2 = (const float*)d_in[8];
    const float* b2  = (const float*)d_in[9];
    const float* W3  = (const float*)d_in[10];
    const float* as3 = (const float*)d_in[11];
    const float* ad3 = (const float*)d_in[12];
    const float* b3  = (const float*)d_in[13];

    char* ws = (char*)d_ws;
    size_t off = 0;
    auto alloc = [&](size_t bytes) -> void* {
        void* p = ws + off;
        off = (off + bytes + 255) & ~(size_t)255;
        return p;
    };
    int*   flag    = (int*)  alloc(4);
    int*   row_ptr = (int*)  alloc((size_t)(N + 1) * 4);
    int*   colv    = (int*)  alloc((size_t)E * 4);
    int*   cursor  = (int*)  alloc((size_t)N * 4);
    int*   deg     = (int*)  alloc((size_t)N * 4);
    int*   excl    = (int*)  alloc((size_t)N * 4);
    int*   bsum    = (int*)  alloc(256 * 4);
    int*   bincnt  = (int*)  alloc(256 * 4);
    int*   bincur  = (int*)  alloc(256 * 4);
    int*   perm    = (int*)  alloc((size_t)N * 4);
    unsigned short* xbf = (unsigned short*)alloc((size_t)N * 128 * 2);
    unsigned short* Wa1 = (unsigned short*)alloc(16 * 128 * 2);
    unsigned short* Wa2 = (unsigned short*)alloc(16 * 64 * 2);
    unsigned short* Wa3 = (unsigned short*)alloc(16 * 64 * 2);
    unsigned short* Wc1 = (unsigned short*)alloc((size_t)64 * 512 * 2);
    unsigned short* Wc2 = (unsigned short*)alloc((size_t)64 * 256 * 2);
    unsigned short* Wc3 = (unsigned short*)alloc((size_t)48 * 256 * 2);
    float* eav     = (float*)alloc((size_t)N * 8 * 4);
    float* edv     = (float*)alloc((size_t)N * 8 * 4);
    unsigned short* g   = (unsigned short*)alloc((size_t)N * 512 * 2);
    unsigned short* h1  = (unsigned short*)alloc((size_t)N * 64 * 2);
    unsigned short* h2  = (unsigned short*)alloc((size_t)N * 64 * 2);
    (void)ws_size;

    const void* eraw = d_in[1];

    const int X4 = N * 128 / 4;
    const int prepTotal = X4 + 16*128 + 16*64 + 16*64 + 64*512 + 64*256 + 48*256;
    initprep_kernel<<<(prepTotal + 255) / 256, 256, 0, stream>>>(
        (const unsigned long long*)eraw, flag, deg, bincnt, N, x, xbf, X4,
        W1, as1, ad1, W2, as2, ad2, W3, as3, ad3,
        Wa1, Wa2, Wa3, Wc1, Wc2, Wc3);

    hist_kernel<<<(E + 255) / 256, 256, 0, stream>>>(eraw, flag, deg, E);
    const int nbScan = (N + 511) / 512;   // 98 <= 256
    scan1_kernel<<<nbScan, 512, 0, stream>>>(deg, excl, bsum, bincnt, N);
    scan2_kernel<<<1, 256, 0, stream>>>(bsum, nbScan, bincnt, bincur);
    scan3_kernel<<<(N + 255) / 256, 256, 0, stream>>>(excl, bsum, deg, row_ptr, cursor,
                                                      bincur, perm, N, E);
    scatter_kernel<<<(E + 255) / 256, 256, 0, stream>>>(eraw, flag, cursor, colv, E);

    const int nodeBlocks = N / 4;              // 12500
    const int mBlocks = (N + 63) / 64;         // 782

    // layer 1: features x (K=128); alpha for layer 2 fused into pgemm1
    agemm_kernel<128><<<mBlocks, 256, 0, stream>>>(xbf, Wa1, eav, edv, N);
    gather_kernel<128><<<nodeBlocks, 256, 0, stream>>>(xbf, row_ptr, colv, perm, eav, edv, g);
    pgemm_kernel<512, 64, false, true><<<mBlocks, 256, 0, stream>>>(g, Wc1, b1, h1, Wa2, eav, edv, N);

    // layer 2: features h1 (K=64); alpha for layer 3 fused into pgemm2
    gather_kernel<64><<<nodeBlocks, 256, 0, stream>>>(h1, row_ptr, colv, perm, eav, edv, g);
    pgemm_kernel<256, 64, false, true><<<mBlocks, 256, 0, stream>>>(g, Wc2, b2, h2, Wa3, eav, edv, N);

    // layer 3: features h2 (K=64) + fused log_softmax
    gather_kernel<64><<<nodeBlocks, 256, 0, stream>>>(h2, row_ptr, colv, perm, eav, edv, g);
    pgemm_kernel<256, 40, true, false><<<mBlocks, 256, 0, stream>>>(g, Wc3, b3, d_out, nullptr, nullptr, nullptr, N);
}

// Round 15
// 420.018 us; speedup vs baseline: 1.6489x; 1.6489x over previous
//
#include <hip/hip_runtime.h>
#include <math.h>

#define NNODES 50000
#define NEG_SLOPE 0.2f

typedef unsigned short ushort8v __attribute__((ext_vector_type(8)));
typedef unsigned short ushort4v __attribute__((ext_vector_type(4)));
typedef short short8v __attribute__((ext_vector_type(8)));
typedef float f32x4 __attribute__((ext_vector_type(4)));
typedef float f32x2 __attribute__((ext_vector_type(2)));

__device__ __forceinline__ unsigned short f2bf(float f){
    unsigned u = __float_as_uint(f);
    u += 0x7fff + ((u >> 16) & 1);   // RNE; inputs finite
    return (unsigned short)(u >> 16);
}

// ---------------- prep helpers ----------------
__device__ __forceinline__ void emit_wa(const float* __restrict__ W, const float* __restrict__ a_s,
                                        const float* __restrict__ a_d, unsigned short* __restrict__ Wt,
                                        int Kin, int C, int id){
    const int n = id / Kin, k = id - n * Kin;
    float v = 0.f;
    if(n < 8){
        const int hh = n & 3;
        const float* av = (n < 4) ? a_s : a_d;
        for(int c = 0; c < C; c++) v += W[(size_t)k * (4 * C) + hh * C + c] * av[hh * C + c];
    }
    Wt[id] = f2bf(v);
}

__device__ __forceinline__ void emit_wc(const float* __restrict__ W, unsigned short* __restrict__ Wt,
                                        int Kin, int C, int id){
    const int c = id / (4 * Kin);
    const int hk = id - c * (4 * Kin);
    const int h = hk / Kin, k = hk - h * Kin;
    const float v = (c < C) ? W[(size_t)k * (4 * C) + h * C + c] * 0.25f : 0.f;
    Wt[id] = f2bf(v);
}

// ---------------- init+prep: detect (block 0) + zero deg + xbf + Wa* + Wc* ----------------
__global__ void initprep_kernel(const unsigned long long* __restrict__ e, int* __restrict__ flag,
                                int* __restrict__ deg, int N,
                                const float* __restrict__ x, unsigned short* __restrict__ xbf, int X4,
                                const float* __restrict__ W1, const float* __restrict__ as1, const float* __restrict__ ad1,
                                const float* __restrict__ W2, const float* __restrict__ as2, const float* __restrict__ ad2,
                                const float* __restrict__ W3, const float* __restrict__ as3, const float* __restrict__ ad3,
                                unsigned short* __restrict__ Wa1, unsigned short* __restrict__ Wa2,
                                unsigned short* __restrict__ Wa3, unsigned short* __restrict__ Wc1,
                                unsigned short* __restrict__ Wc2, unsigned short* __restrict__ Wc3){
    if(blockIdx.x == 0 && threadIdx.x < 64){
        const unsigned long long v = e[threadIdx.x];
        const unsigned long long mask = __ballot(v >= (1ULL << 32));
        if(threadIdx.x == 0) *flag = (mask == 0ULL) ? 1 : 0;
    }
    int id = blockIdx.x * blockDim.x + threadIdx.x;
    if(id < N) deg[id] = 0;
    if(id < X4){
        const float4 v = *(const float4*)&x[(size_t)id * 4];
        ushort4v o;
        o[0] = f2bf(v.x); o[1] = f2bf(v.y); o[2] = f2bf(v.z); o[3] = f2bf(v.w);
        *(ushort4v*)&xbf[(size_t)id * 4] = o;
        return;
    }
    id -= X4;
    if(id < 16 * 128){ emit_wa(W1, as1, ad1, Wa1, 128, 64, id); return; }
    id -= 16 * 128;
    if(id < 16 * 64){ emit_wa(W2, as2, ad2, Wa2, 64, 64, id); return; }
    id -= 16 * 64;
    if(id < 16 * 64){ emit_wa(W3, as3, ad3, Wa3, 64, 40, id); return; }
    id -= 16 * 64;
    if(id < 64 * 512){ emit_wc(W1, Wc1, 128, 64, id); return; }
    id -= 64 * 512;
    if(id < 64 * 256){ emit_wc(W2, Wc2, 64, 64, id); return; }
    id -= 64 * 256;
    if(id < 48 * 256){ emit_wc(W3, Wc3, 64, 40, id); }
}

// ---------------- histogram off the raw edge buffer ----------------
__global__ void hist_kernel(const void* __restrict__ e, const int* __restrict__ flag,
                            int* __restrict__ deg, int E){
    const int i = blockIdx.x * blockDim.x + threadIdx.x;
    if(i < E){
        const int d = (*flag) ? (int)((const long long*)e)[E + i] : ((const int*)e)[E + i];
        atomicAdd(&deg[d], 1);
    }
}

// ---------------- CSR build (hierarchical scan) ----------------
__global__ __launch_bounds__(512) void scan1_kernel(const int* __restrict__ deg,
                                                    int* __restrict__ excl,
                                                    int* __restrict__ bsum, int n){
    __shared__ int sh[512];
    const int t = threadIdx.x;
    const int gid = blockIdx.x * 512 + t;
    const int v = (gid < n) ? deg[gid] : 0;
    sh[t] = v;
    __syncthreads();
    for(int off = 1; off < 512; off <<= 1){
        const int add = (t >= off) ? sh[t - off] : 0;
        __syncthreads();
        sh[t] += add;
        __syncthreads();
    }
    if(gid < n) excl[gid] = sh[t] - v;
    if(t == 511) bsum[blockIdx.x] = sh[511];
}

__global__ __launch_bounds__(128) void scan2_kernel(int* __restrict__ bsum, int nb){
    __shared__ int sh[128];
    const int t = threadIdx.x;
    const int v = (t < nb) ? bsum[t] : 0;
    sh[t] = v;
    __syncthreads();
    for(int off = 1; off < 128; off <<= 1){
        const int add = (t >= off) ? sh[t - off] : 0;
        __syncthreads();
        sh[t] += add;
        __syncthreads();
    }
    if(t < nb) bsum[t] = sh[t] - v;
}

__global__ void scan3_kernel(const int* __restrict__ excl, const int* __restrict__ bsum,
                             int* __restrict__ row_ptr, int* __restrict__ cursor,
                             int n, int E){
    const int gid = blockIdx.x * blockDim.x + threadIdx.x;
    if(gid < n){
        const int r = excl[gid] + bsum[gid >> 9];
        row_ptr[gid] = r;
        cursor[gid] = r;
    }
    if(gid == 0) row_ptr[n] = E;
}

__global__ void scatter_kernel(const void* __restrict__ e, const int* __restrict__ flag,
                               int* __restrict__ cursor, int* __restrict__ col, int E){
    const int i = blockIdx.x * blockDim.x + threadIdx.x;
    if(i < E){
        int s, d;
        if(*flag){ s = (int)((const long long*)e)[i]; d = (int)((const long long*)e)[E + i]; }
        else     { s = ((const int*)e)[i];            d = ((const int*)e)[E + i]; }
        const int pos = atomicAdd(&cursor[d], 1);
        col[pos] = s;
    }
}

// ---------------- alpha GEMM (layer 1 only): ea/ed = exp(A @ Wa) ----------------
template<int K>
__global__ __launch_bounds__(256) void agemm_kernel(const unsigned short* __restrict__ A,
                                                    const unsigned short* __restrict__ Wa,
                                                    float* __restrict__ ea, float* __restrict__ ed,
                                                    int M){
    const int lane = threadIdx.x & 63;
    const int wave = threadIdx.x >> 6;
    const int quad = lane >> 4;
    const int l16 = lane & 15;
    const int bm = blockIdx.x * 64;
    const int m = min(bm + wave * 16 + l16, M - 1);
    f32x4 acc = {0,0,0,0};
    #pragma unroll
    for(int k0 = 0; k0 < K; k0 += 32){
        const short8v a = *(const short8v*)&A[(size_t)m * K + k0 + quad * 8];
        const short8v b = *(const short8v*)&Wa[(size_t)l16 * K + k0 + quad * 8];
        acc = __builtin_amdgcn_mfma_f32_16x16x32_bf16(a, b, acc, 0, 0, 0);
    }
    if(l16 < 8){
        const int h = l16 & 3;
        float* dst = (l16 < 4) ? ea : ed;
        const int rbase = bm + wave * 16 + quad * 4;
        #pragma unroll
        for(int r = 0; r < 4; r++){
            const int row = rbase + r;
            if(row < M){
                const float v = acc[r];
                *(f32x2*)&dst[(size_t)row * 8 + 2 * h] = (f32x2){__expf(v), __expf(NEG_SLOPE * v)};
            }
        }
    }
}

// ---------------- gather RAW features (round-9 shape, verbatim) ----------------
template<int K>
__global__ __launch_bounds__(256) void gather_kernel(const unsigned short* __restrict__ X,
                                                     const int* __restrict__ row_ptr,
                                                     const int* __restrict__ col,
                                                     const float* __restrict__ ea,
                                                     const float* __restrict__ ed,
                                                     unsigned short* __restrict__ g){
    constexpr int CPL = K / 16;       // channels per lane: 8 or 4
    constexpr int PAIRS = CPL / 2;
    const int lane = threadIdx.x & 63;
    const int wave = threadIdx.x >> 6;
    const int n = blockIdx.x * 4 + wave;
    const int slot = lane >> 4;
    const int pos = lane & 15;
    const int rs = row_ptr[n], re = row_ptr[n + 1];
    const int T = re - rs + 1;        // edges + virtual self loop
    const float4 edA = *(const float4*)&ed[(size_t)n * 8];
    const float4 edB = *(const float4*)&ed[(size_t)n * 8 + 4];

    f32x2 acc[4][PAIRS];
    #pragma unroll
    for(int h = 0; h < 4; h++)
        #pragma unroll
        for(int p = 0; p < PAIRS; p++) acc[h][p] = (f32x2){0.f, 0.f};
    float dnm[4] = {0.f, 0.f, 0.f, 0.f};

    auto body = [&](int e){
        const int s = (e < re) ? col[e] : n;   // e==re => self loop
        const float4 eaA = *(const float4*)&ea[(size_t)s * 8];
        const float4 eaB = *(const float4*)&ea[(size_t)s * 8 + 4];
        const float w0 = fmaxf(eaA.x * edA.x, eaA.y * edA.y);
        const float w1 = fmaxf(eaA.z * edA.z, eaA.w * edA.w);
        const float w2 = fmaxf(eaB.x * edB.x, eaB.y * edB.y);
        const float w3 = fmaxf(eaB.z * edB.z, eaB.w * edB.w);
        dnm[0] += w0; dnm[1] += w1; dnm[2] += w2; dnm[3] += w3;
        unsigned u[PAIRS];
        if constexpr(PAIRS == 2){
            const uint2 t2 = *(const uint2*)&X[(size_t)s * K + pos * CPL];
            u[0] = t2.x; u[1] = t2.y;
        } else {
            const uint4 t4 = *(const uint4*)&X[(size_t)s * K + pos * CPL];
            u[0] = t4.x; u[1] = t4.y; u[2] = t4.z; u[3] = t4.w;
        }
        #pragma unroll
        for(int p = 0; p < PAIRS; p++){
            const f32x2 v = {__uint_as_float(u[p] << 16), __uint_as_float(u[p] & 0xffff0000u)};
            acc[0][p] += (f32x2){w0, w0} * v;
            acc[1][p] += (f32x2){w1, w1} * v;
            acc[2][p] += (f32x2){w2, w2} * v;
            acc[3][p] += (f32x2){w3, w3} * v;
        }
    };

    int k = 0;
    for(; k + 8 <= T; k += 8){ body(rs + k + slot); body(rs + k + 4 + slot); }
    for(; k + 4 <= T; k += 4){ body(rs + k + slot); }
    if(k < T && slot < T - k){ body(rs + k + slot); }

    #pragma unroll
    for(int msk = 16; msk < 64; msk <<= 1){
        #pragma unroll
        for(int h = 0; h < 4; h++){
            #pragma unroll
            for(int p = 0; p < PAIRS; p++){
                acc[h][p][0] += __shfl_xor(acc[h][p][0], msk);
                acc[h][p][1] += __shfl_xor(acc[h][p][1], msk);
            }
            dnm[h] += __shfl_xor(dnm[h], msk);
        }
    }
    if(lane < 16){
        #pragma unroll
        for(int h = 0; h < 4; h++){
            const float sc = 1.f / dnm[h];
            if constexpr(PAIRS == 2){
                ushort4v o;
                o[0] = f2bf(acc[h][0][0] * sc); o[1] = f2bf(acc[h][0][1] * sc);
                o[2] = f2bf(acc[h][1][0] * sc); o[3] = f2bf(acc[h][1][1] * sc);
                *(ushort4v*)&g[(size_t)n * (4 * K) + h * K + pos * CPL] = o;
            } else {
                ushort8v o;
                #pragma unroll
                for(int p = 0; p < 4; p++){
                    o[2*p]   = f2bf(acc[h][p][0] * sc);
                    o[2*p+1] = f2bf(acc[h][p][1] * sc);
                }
                *(ushort8v*)&g[(size_t)n * (4 * K) + h * K + pos * CPL] = o;
            }
        }
    }
}

// ---------------- post-aggregation GEMM (+fused next-layer alpha) ----------------
// out = g[n,KC] @ Wcat + bias, relu -> h bf16 (or FINAL log_softmax, fp32).
// ALPHA: each wave round-trips its own 16 bf16 h-rows through LDS (no block
// barrier -- wave-private tile) and runs 2 MFMAs vs Wa (K=64) to emit the next
// layer's pre-exponentiated ea/ed. Uses bf16-rounded h => bit-compatible with
// the standalone agemm it replaces.
template<int KC, int NC, bool FINAL, bool ALPHA>
__global__ __launch_bounds__(256) void pgemm_kernel(const unsigned short* __restrict__ A,
                                                    const unsigned short* __restrict__ Bt,
                                                    const float* __restrict__ bias,
                                                    void* __restrict__ outv,
                                                    const unsigned short* __restrict__ Wa,
                                                    float* __restrict__ ea,
                                                    float* __restrict__ ed,
                                                    int M){
    constexpr int NT = (NC + 15) / 16;   // 4 (NC=64) or 3 (NC=40)
    __shared__ unsigned short lh[ALPHA ? 4 : 1][16][72];   // 72-stride: 16B-aligned rows, 2-way banks
    const int lane = threadIdx.x & 63;
    const int wave = threadIdx.x >> 6;
    const int quad = lane >> 4;
    const int l16 = lane & 15;
    const int bm = blockIdx.x * 64;
    const int m = min(bm + wave * 16 + l16, M - 1);
    const size_t arow = (size_t)m * KC;

    f32x4 acc[NT];
    #pragma unroll
    for(int t = 0; t < NT; t++) acc[t] = (f32x4){0,0,0,0};

    for(int k0 = 0; k0 < KC; k0 += 32){
        const short8v a = *(const short8v*)&A[arow + k0 + quad * 8];
        #pragma unroll
        for(int t = 0; t < NT; t++){
            const short8v b = *(const short8v*)&Bt[(size_t)(t * 16 + l16) * KC + k0 + quad * 8];
            acc[t] = __builtin_amdgcn_mfma_f32_16x16x32_bf16(a, b, acc[t], 0, 0, 0);
        }
    }
    const int rbase = bm + wave * 16 + quad * 4;
    if(!FINAL){
        unsigned short* out = (unsigned short*)outv;
        #pragma unroll
        for(int t = 0; t < NT; t++){
            const int c = t * 16 + l16;
            #pragma unroll
            for(int r = 0; r < 4; r++){
                const unsigned short hb = f2bf(fmaxf(acc[t][r] + bias[c], 0.f));
                const int row = rbase + r;
                if(row < M) out[(size_t)row * NC + c] = hb;
                if constexpr(ALPHA) lh[wave][quad * 4 + r][c] = hb;
            }
        }
        if constexpr(ALPHA){
            // wave-private LDS tile: within-wave lgkmcnt ordering suffices (no barrier)
            f32x4 a4 = {0, 0, 0, 0};
            #pragma unroll
            for(int k0 = 0; k0 < 64; k0 += 32){
                const short8v a = *(const short8v*)&lh[wave][l16][k0 + quad * 8];
                const short8v b = *(const short8v*)&Wa[(size_t)l16 * 64 + k0 + quad * 8];
                a4 = __builtin_amdgcn_mfma_f32_16x16x32_bf16(a, b, a4, 0, 0, 0);
            }
            if(l16 < 8){
                const int h = l16 & 3;
                float* dst = (l16 < 4) ? ea : ed;
                #pragma unroll
                for(int r = 0; r < 4; r++){
                    const int row = rbase + r;
                    if(row < M){
                        const float v = a4[r];
                        *(f32x2*)&dst[(size_t)row * 8 + 2 * h] = (f32x2){__expf(v), __expf(NEG_SLOPE * v)};
                    }
                }
            }
        }
    } else {
        float* out = (float*)outv;
        float o[NT][4];
        #pragma unroll
        for(int t = 0; t < NT; t++){
            const int c = t * 16 + l16;
            const bool valid = c < 40;
            const float bc = valid ? bias[c] : 0.f;
            #pragma unroll
            for(int r = 0; r < 4; r++)
                o[t][r] = valid ? fmaxf(acc[t][r] + bc, 0.f) : -INFINITY;
        }
        #pragma unroll
        for(int r = 0; r < 4; r++){
            float mx = o[0][r];
            #pragma unroll
            for(int t = 1; t < NT; t++) mx = fmaxf(mx, o[t][r]);
            #pragma unroll
            for(int off = 1; off < 16; off <<= 1) mx = fmaxf(mx, __shfl_xor(mx, off));
            float se = 0.f;
            #pragma unroll
            for(int t = 0; t < NT; t++) se += (o[t][r] > -INFINITY) ? __expf(o[t][r] - mx) : 0.f;
            #pragma unroll
            for(int off = 1; off < 16; off <<= 1) se += __shfl_xor(se, off);
            const float lz = mx + logf(se);
            const int row = rbase + r;
            if(row < M){
                #pragma unroll
                for(int t = 0; t < NT; t++){
                    const int c = t * 16 + l16;
                    if(c < 40) out[(size_t)row * 40 + c] = o[t][r] - lz;
                }
            }
        }
    }
}

// ---------------- driver ----------------
extern "C" void kernel_launch(void* const* d_in, const int* in_sizes, int n_in,
                              void* d_out, int out_size, void* d_ws, size_t ws_size,
                              hipStream_t stream){
    const int N = NNODES;
    const int E = in_sizes[1] / 2;

    const float* x   = (const float*)d_in[0];
    const float* W1  = (const float*)d_in[2];
    const float* as1 = (const float*)d_in[3];
    const float* ad1 = (const float*)d_in[4];
    const float* b1  = (const float*)d_in[5];
    const float* W2  = (const float*)d_in[6];
    const float* as2 = (const float*)d_in[7];
    const float* ad2 = (const float*)d_in[8];
    const float* b2  = (const float*)d_in[9];
    const float* W3  = (const float*)d_in[10];
    const float* as3 = (const float*)d_in[11];
    const float* ad3 = (const float*)d_in[12];
    const float* b3  = (const float*)d_in[13];

    char* ws = (char*)d_ws;
    size_t off = 0;
    auto alloc = [&](size_t bytes) -> void* {
        void* p = ws + off;
        off = (off + bytes + 255) & ~(size_t)255;
        return p;
    };
    int*   flag    = (int*)  alloc(4);
    int*   row_ptr = (int*)  alloc((size_t)(N + 1) * 4);
    int*   colv    = (int*)  alloc((size_t)E * 4);
    int*   cursor  = (int*)  alloc((size_t)N * 4);
    int*   deg     = (int*)  alloc((size_t)N * 4);
    int*   excl    = (int*)  alloc((size_t)N * 4);
    int*   bsum    = (int*)  alloc(128 * 4);
    unsigned short* xbf = (unsigned short*)alloc((size_t)N * 128 * 2);
    unsigned short* Wa1 = (unsigned short*)alloc(16 * 128 * 2);
    unsigned short* Wa2 = (unsigned short*)alloc(16 * 64 * 2);
    unsigned short* Wa3 = (unsigned short*)alloc(16 * 64 * 2);
    unsigned short* Wc1 = (unsigned short*)alloc((size_t)64 * 512 * 2);
    unsigned short* Wc2 = (unsigned short*)alloc((size_t)64 * 256 * 2);
    unsigned short* Wc3 = (unsigned short*)alloc((size_t)48 * 256 * 2);
    float* eav     = (float*)alloc((size_t)N * 8 * 4);
    float* edv     = (float*)alloc((size_t)N * 8 * 4);
    unsigned short* g   = (unsigned short*)alloc((size_t)N * 512 * 2);
    unsigned short* h1  = (unsigned short*)alloc((size_t)N * 64 * 2);
    unsigned short* h2  = (unsigned short*)alloc((size_t)N * 64 * 2);
    (void)ws_size;

    const void* eraw = d_in[1];

    const int X4 = N * 128 / 4;
    const int prepTotal = X4 + 16*128 + 16*64 + 16*64 + 64*512 + 64*256 + 48*256;
    initprep_kernel<<<(prepTotal + 255) / 256, 256, 0, stream>>>(
        (const unsigned long long*)eraw, flag, deg, N, x, xbf, X4,
        W1, as1, ad1, W2, as2, ad2, W3, as3, ad3,
        Wa1, Wa2, Wa3, Wc1, Wc2, Wc3);

    hist_kernel<<<(E + 255) / 256, 256, 0, stream>>>(eraw, flag, deg, E);
    const int nbScan = (N + 511) / 512;
    scan1_kernel<<<nbScan, 512, 0, stream>>>(deg, excl, bsum, N);
    scan2_kernel<<<1, 128, 0, stream>>>(bsum, nbScan);
    scan3_kernel<<<(N + 255) / 256, 256, 0, stream>>>(excl, bsum, row_ptr, cursor, N, E);
    scatter_kernel<<<(E + 255) / 256, 256, 0, stream>>>(eraw, flag, cursor, colv, E);

    const int nodeBlocks = N / 4;              // 12500
    const int mBlocks = (N + 63) / 64;         // 782

    // layer 1: features x (K=128); alpha for layer 2 fused into pgemm1
    agemm_kernel<128><<<mBlocks, 256, 0, stream>>>(xbf, Wa1, eav, edv, N);
    gather_kernel<128><<<nodeBlocks, 256, 0, stream>>>(xbf, row_ptr, colv, eav, edv, g);
    pgemm_kernel<512, 64, false, true><<<mBlocks, 256, 0, stream>>>(g, Wc1, b1, h1, Wa2, eav, edv, N);

    // layer 2: features h1 (K=64); alpha for layer 3 fused into pgemm2
    gather_kernel<64><<<nodeBlocks, 256, 0, stream>>>(h1, row_ptr, colv, eav, edv, g);
    pgemm_kernel<256, 64, false, true><<<mBlocks, 256, 0, stream>>>(g, Wc2, b2, h2, Wa3, eav, edv, N);

    // layer 3: features h2 (K=64) + fused log_softmax
    gather_kernel<64><<<nodeBlocks, 256, 0, stream>>>(h2, row_ptr, colv, eav, edv, g);
    pgemm_kernel<256, 40, true, false><<<mBlocks, 256, 0, stream>>>(g, Wc3, b3, d_out, nullptr, nullptr, nullptr, N);
}